// Round 6
// baseline (704.084 us; speedup 1.0000x reference)
//
#include <hip/hip_runtime.h>
#include <hip/hip_bf16.h>
#include <stdint.h>

#define B_SZ 4
#define H_N 8
#define S_LEN 2048
#define D_HEAD 256
#define HD 2048

typedef __attribute__((ext_vector_type(8))) short bf16x8;
typedef __attribute__((ext_vector_type(4))) float f32x4;
typedef __hip_bfloat16 bf16;

typedef __attribute__((address_space(1))) const void glob_cv;
typedef __attribute__((address_space(3))) void lds_v;

__device__ __forceinline__ short f2bf(float f) {
  bf16 h = __float2bfloat16(f);
  return *reinterpret_cast<short*>(&h);
}

// ---------------- f32 -> bf16 convert (weights) ----------------
__global__ __launch_bounds__(256) void cvt_kernel(const float* __restrict__ src,
                                                  bf16* __restrict__ dst, int n) {
  int i = (blockIdx.x * 256 + threadIdx.x) * 8;
  if (i + 7 < n) {
    float4 a = *(const float4*)(src + i);
    float4 b = *(const float4*)(src + i + 4);
    bf16x8 o;
    o[0] = f2bf(a.x); o[1] = f2bf(a.y); o[2] = f2bf(a.z); o[3] = f2bf(a.w);
    o[4] = f2bf(b.x); o[5] = f2bf(b.y); o[6] = f2bf(b.z); o[7] = f2bf(b.w);
    *reinterpret_cast<bf16x8*>(dst + i) = o;
  }
}

// ---------------- projection GEMM: X[8192,256] @ W[2048,256]^T + b ----------------
__global__ __launch_bounds__(256) void proj_gemm(const float* __restrict__ X,
                                                 const bf16* __restrict__ W,
                                                 const float* __restrict__ bias,
                                                 bf16* __restrict__ Out, float scale,
                                                 int vtrans) {
  int tid = threadIdx.x;
  int w = tid >> 6, l = tid & 63;
  int l15 = l & 15, lg = l >> 4;
  int m0 = blockIdx.x * 64 + w * 16;
  int n0 = blockIdx.y * 64;

  f32x4 acc[4];
#pragma unroll
  for (int n = 0; n < 4; ++n) acc[n] = f32x4{0.f, 0.f, 0.f, 0.f};

  const float* xrow = X + (size_t)(m0 + l15) * 256 + lg * 8;
#pragma unroll
  for (int kb = 0; kb < 8; ++kb) {
    float4 xa = *(const float4*)(xrow + kb * 32);
    float4 xb = *(const float4*)(xrow + kb * 32 + 4);
    bf16x8 af;
    af[0] = f2bf(xa.x); af[1] = f2bf(xa.y); af[2] = f2bf(xa.z); af[3] = f2bf(xa.w);
    af[4] = f2bf(xb.x); af[5] = f2bf(xb.y); af[6] = f2bf(xb.z); af[7] = f2bf(xb.w);
#pragma unroll
    for (int n = 0; n < 4; ++n) {
      bf16x8 wf = *(const bf16x8*)(W + (size_t)(n0 + n * 16 + l15) * 256 + kb * 32 + lg * 8);
      acc[n] = __builtin_amdgcn_mfma_f32_16x16x32_bf16(af, wf, acc[n], 0, 0, 0);
    }
  }
#pragma unroll
  for (int n = 0; n < 4; ++n) {
    int e = n0 + n * 16 + l15;
    float bv = bias[e];
#pragma unroll
    for (int r = 0; r < 4; ++r) {
      int m = m0 + lg * 4 + r;
      int b = m >> 11, s = m & 2047;
      int h = s >> 8;
      int sp = ((s & 255) << 3) | (e >> 8);
      int d = e & 255;
      size_t off = vtrans
          ? (((size_t)(b * 8 + h) * D_HEAD) + d) * S_LEN + sp       // [B*H, D, S']
          : (((size_t)(b * 8 + h) * S_LEN) + sp) * D_HEAD + d;      // [B*H, S', D]
      Out[off] = __float2bfloat16((acc[n][r] + bv) * scale);
    }
  }
}

// ---------------- flash attention ----------------
// 1024 blocks (XCD remap); 4 waves x 16 q-rows; KVBLK=32.
// K/V tiles DOUBLE-BUFFERED via global_load_lds with counted vmcnt(8):
// loads for tile t+1 issued at top of iter t; wait only for tile t's loads.
//   per buffer: K [0,8192), V [8192,16384) elems (32 KB), x2 buffers = 64 KB
__global__ __launch_bounds__(256, 2) void attn_kernel(const bf16* __restrict__ Qp,
                                                      const bf16* __restrict__ Kp,
                                                      const bf16* __restrict__ Vt,
                                                      bf16* __restrict__ AL) {
  __shared__ __align__(16) bf16 KVs[2 * 16384];    // 64 KB
  __shared__ __align__(16) bf16 Ps[4][16 * 40];    // per-wave P tile, 5 KB

  int tid = threadIdx.x;
  int w = tid >> 6, l = tid & 63;
  int l15 = l & 15, lg = l >> 4;
  int l31 = l & 31, hl = l >> 5;

  // XCD-aware remap: xcd = bid&7; qt cycles fastest within a head
  int bid = blockIdx.x;
  int xcd = bid & 7, j = bid >> 3;
  int bh = xcd + 8 * (j >> 5);
  int qt = j & 31;

  const bf16* Qb = Qp + (size_t)bh * S_LEN * D_HEAD;
  const bf16* Kb = Kp + (size_t)bh * S_LEN * D_HEAD;
  const bf16* Vb = Vt + (size_t)bh * (size_t)D_HEAD * S_LEN;

  int q0 = qt * 64 + w * 16;

  bf16x8 qf[8];
#pragma unroll
  for (int kb = 0; kb < 8; ++kb)
    qf[kb] = *(const bf16x8*)(Qb + (size_t)(q0 + l15) * D_HEAD + kb * 32 + lg * 8);

  f32x4 acc[16];
#pragma unroll
  for (int n = 0; n < 16; ++n) acc[n] = f32x4{0.f, 0.f, 0.f, 0.f};
  f32x4 acc_l = f32x4{0.f, 0.f, 0.f, 0.f};   // softmax denom via ones-column MFMA
  float m_r[4] = {-__builtin_inff(), -__builtin_inff(), -__builtin_inff(), -__builtin_inff()};

  bf16x8 ones;
#pragma unroll
  for (int i = 0; i < 8; ++i) ones[i] = (short)0x3F80;

  const float THR = 4.0f;   // defer-max threshold (T13)

  // per-lane DMA source pointers (advanced per issued tile)
  // waves 0,1 stage K: src = Kb + kv(l31)*512B + (cd = w*16 + i*2 + hl)*16B
  // waves 2,3 stage V: src = Vb + d(lane)*4096B + kvc((w-2)*2 + i>>2)*16B
  const char* pK = (const char*)Kb + (size_t)l31 * 512 + (size_t)(w * 256 + hl * 16);
  const char* pV = (const char*)Vb + (size_t)l * 4096 + (size_t)((w - 2) * 32);
  // per-lane LDS dest byte offsets within a buffer
  int dK = w * 8192 + l * 16;                // waves 0,1 (byte)
  int dV = 16384 + (w - 2) * 8192 + l * 16;  // waves 2,3 (byte)
  char* ldsBase = (char*)&KVs[0];

  auto ISSUE = [&](int buf) {
    char* bb = ldsBase + buf * 32768;
    if (w < 2) {
#pragma unroll
      for (int i = 0; i < 8; ++i)
        __builtin_amdgcn_global_load_lds((glob_cv*)(pK + i * 32),
                                         (lds_v*)(bb + dK + i * 1024), 16, 0, 0);
      pK += 32 * 512;
    } else {
#pragma unroll
      for (int i = 0; i < 8; ++i)
        __builtin_amdgcn_global_load_lds((glob_cv*)(pV + (i & 3) * 262144 + (i >> 2) * 16),
                                         (lds_v*)(bb + dV + i * 1024), 16, 0, 0);
      pV += 64;
    }
  };

  int krd = lg * 256 + l15 * 8;            // K frag base (elems, within buffer)
  int vrd = 8192 + lg * 2048 + l15 * 8;    // V frag base (elems, within buffer)
  int prd = l15 * 40 + lg * 8;

  ISSUE(0);   // tile 0 -> buf 0 (no drain; waited via vmcnt below)

  for (int kt = 0; kt < 64; ++kt) {
    int cur = kt & 1;
    if (kt < 63) ISSUE(cur ^ 1);           // tile kt+1 -> other buffer
    if (kt < 63) {
      asm volatile("s_waitcnt vmcnt(8)" ::: "memory");   // tile kt's 8 loads done
    } else {
      asm volatile("s_waitcnt vmcnt(0)" ::: "memory");
    }
    __builtin_amdgcn_s_barrier();          // all waves' tile-kt loads landed
    __builtin_amdgcn_sched_barrier(0);

    const bf16* bufp = &KVs[cur * 16384];

    // ---- QK^T from LDS ----
    f32x4 sc0 = f32x4{0.f, 0.f, 0.f, 0.f}, sc1 = f32x4{0.f, 0.f, 0.f, 0.f};
    __builtin_amdgcn_s_setprio(1);
#pragma unroll
    for (int kb = 0; kb < 8; ++kb) {
      bf16x8 kf0 = *(const bf16x8*)(bufp + krd + kb * 1024);
      bf16x8 kf1 = *(const bf16x8*)(bufp + krd + kb * 1024 + 128);
      sc0 = __builtin_amdgcn_mfma_f32_16x16x32_bf16(qf[kb], kf0, sc0, 0, 0, 0);
      sc1 = __builtin_amdgcn_mfma_f32_16x16x32_bf16(qf[kb], kf1, sc1, 0, 0, 0);
    }
    __builtin_amdgcn_s_setprio(0);

    // ---- online softmax with defer-max ----
    float pm[4];
#pragma unroll
    for (int r = 0; r < 4; ++r) {
      float v = fmaxf(sc0[r], sc1[r]);
      v = fmaxf(v, __shfl_xor(v, 1));
      v = fmaxf(v, __shfl_xor(v, 2));
      v = fmaxf(v, __shfl_xor(v, 4));
      v = fmaxf(v, __shfl_xor(v, 8));
      pm[r] = v;
    }
    bool need = (pm[0] > m_r[0] + THR) || (pm[1] > m_r[1] + THR) ||
                (pm[2] > m_r[2] + THR) || (pm[3] > m_r[3] + THR);
    if (__ballot(need)) {
#pragma unroll
      for (int r = 0; r < 4; ++r) {
        float mn = fmaxf(m_r[r], pm[r]);
        float esc = __expf(m_r[r] - mn);
        m_r[r] = mn;
#pragma unroll
        for (int n = 0; n < 16; ++n) acc[n][r] *= esc;
        acc_l[r] *= esc;
      }
    }
#pragma unroll
    for (int r = 0; r < 4; ++r) {
      float p0 = __expf(sc0[r] - m_r[r]);
      float p1 = __expf(sc1[r] - m_r[r]);
      int qr = lg * 4 + r;
      Ps[w][qr * 40 + l15] = __float2bfloat16(p0);
      Ps[w][qr * 40 + 16 + l15] = __float2bfloat16(p1);
    }

    // ---- PV from LDS (+ ones-column for denominator) ----
    bf16x8 pa = *(const bf16x8*)(&Ps[w][prd]);
    __builtin_amdgcn_s_setprio(1);
    acc_l = __builtin_amdgcn_mfma_f32_16x16x32_bf16(pa, ones, acc_l, 0, 0, 0);
#pragma unroll
    for (int n = 0; n < 16; ++n) {
      bf16x8 vbf = *(const bf16x8*)(bufp + vrd + n * 128);
      acc[n] = __builtin_amdgcn_mfma_f32_16x16x32_bf16(pa, vbf, acc[n], 0, 0, 0);
    }
    __builtin_amdgcn_s_setprio(0);

    __builtin_amdgcn_s_barrier();          // buf[cur] consumed -> safe to overwrite next iter
  }

  // ---- epilogue: normalize, store to attn_lin[b, s', h*256+d] ----
  int b = bh >> 3, h = bh & 7;
#pragma unroll
  for (int r = 0; r < 4; ++r) {
    float inv = 1.0f / acc_l[r];
    int q = q0 + lg * 4 + r;
    bf16* orow = AL + ((size_t)b * S_LEN + q) * HD + h * D_HEAD;
#pragma unroll
    for (int n = 0; n < 16; ++n)
      orow[n * 16 + l15] = __float2bfloat16(acc[n][r] * inv);
  }
}

// ---------------- output GEMM: AL[8192,2048] @ Wo[256,2048]^T + bo -> f32 ----------------
__global__ __launch_bounds__(256) void out_gemm(const bf16* __restrict__ A,
                                                const bf16* __restrict__ W,
                                                const float* __restrict__ bias,
                                                float* __restrict__ Out) {
  int tid = threadIdx.x;
  int w = tid >> 6, l = tid & 63;
  int l15 = l & 15, lg = l >> 4;
  int m0 = blockIdx.x * 64 + w * 16;
  int n0 = blockIdx.y * 64;
  f32x4 acc[4];
#pragma unroll
  for (int n = 0; n < 4; ++n) acc[n] = f32x4{0.f, 0.f, 0.f, 0.f};
  const bf16* arow = A + (size_t)(m0 + l15) * HD + lg * 8;
#pragma unroll 8
  for (int kb = 0; kb < 64; ++kb) {
    bf16x8 af = *(const bf16x8*)(arow + kb * 32);
#pragma unroll
    for (int n = 0; n < 4; ++n) {
      bf16x8 wf = *(const bf16x8*)(W + (size_t)(n0 + n * 16 + l15) * HD + kb * 32 + lg * 8);
      acc[n] = __builtin_amdgcn_mfma_f32_16x16x32_bf16(af, wf, acc[n], 0, 0, 0);
    }
  }
#pragma unroll
  for (int n = 0; n < 4; ++n) {
    int d = n0 + n * 16 + l15;
    float bv = bias[d];
#pragma unroll
    for (int r = 0; r < 4; ++r)
      Out[(size_t)(m0 + lg * 4 + r) * 256 + d] = acc[n][r] + bv;
  }
}

extern "C" void kernel_launch(void* const* d_in, const int* in_sizes, int n_in,
                              void* d_out, int out_size, void* d_ws, size_t ws_size,
                              hipStream_t stream) {
  (void)in_sizes; (void)n_in; (void)out_size; (void)ws_size;
  const float* query  = (const float*)d_in[0];
  const float* key    = (const float*)d_in[1];
  const float* values = (const float*)d_in[2];
  const float* Wq = (const float*)d_in[3];
  const float* bq = (const float*)d_in[4];
  const float* Wk = (const float*)d_in[5];
  const float* bk = (const float*)d_in[6];
  const float* Wv = (const float*)d_in[7];
  const float* bv = (const float*)d_in[8];
  const float* Wo = (const float*)d_in[9];
  const float* bo = (const float*)d_in[10];
  float* out = (float*)d_out;

  bf16* ws = (bf16*)d_ws;
  const size_t NP = (size_t)B_SZ * H_N * S_LEN * D_HEAD;  // 16,777,216
  const size_t NW = (size_t)HD * D_HEAD;                  // 524,288
  bf16* Qp  = ws;
  bf16* Kp  = Qp + NP;
  bf16* Vtp = Kp + NP;   // V transposed: [B*H, D, S']
  bf16* ALb = Vtp + NP;
  bf16* Wqb = ALb + NP;
  bf16* Wkb = Wqb + NW;
  bf16* Wvb = Wkb + NW;
  bf16* Wob = Wvb + NW;

  cvt_kernel<<<256, 256, 0, stream>>>(Wq, Wqb, (int)NW);
  cvt_kernel<<<256, 256, 0, stream>>>(Wk, Wkb, (int)NW);
  cvt_kernel<<<256, 256, 0, stream>>>(Wv, Wvb, (int)NW);
  cvt_kernel<<<256, 256, 0, stream>>>(Wo, Wob, (int)NW);

  dim3 pg(128, 32);
  proj_gemm<<<pg, 256, 0, stream>>>(query,  Wqb, bq, Qp,  1.0f / 16.0f, 0);  // 1/sqrt(d_k) folded
  proj_gemm<<<pg, 256, 0, stream>>>(key,    Wkb, bk, Kp,  1.0f, 0);
  proj_gemm<<<pg, 256, 0, stream>>>(values, Wvb, bv, Vtp, 1.0f, 1);          // transposed store

  attn_kernel<<<1024, 256, 0, stream>>>(Qp, Kp, Vtp, ALb);

  out_gemm<<<dim3(128, 4), 256, 0, stream>>>(ALb, Wob, bo, out);
}

// Round 7
// 509.278 us; speedup vs baseline: 1.3825x; 1.3825x over previous
//
#include <hip/hip_runtime.h>
#include <hip/hip_bf16.h>
#include <stdint.h>

#define B_SZ 4
#define H_N 8
#define S_LEN 2048
#define D_HEAD 256
#define HD 2048

typedef __attribute__((ext_vector_type(8))) short bf16x8;
typedef __attribute__((ext_vector_type(4))) float f32x4;
typedef __hip_bfloat16 bf16;

typedef __attribute__((address_space(1))) const void glob_cv;
typedef __attribute__((address_space(3))) void lds_v;

__device__ __forceinline__ short f2bf(float f) {
  bf16 h = __float2bfloat16(f);
  return *reinterpret_cast<short*>(&h);
}

// ---------------- f32 -> bf16 convert ----------------
__global__ __launch_bounds__(256) void cvt_kernel(const float* __restrict__ src,
                                                  bf16* __restrict__ dst, int n) {
  int i = (blockIdx.x * 256 + threadIdx.x) * 8;
  if (i + 7 < n) {
    float4 a = *(const float4*)(src + i);
    float4 b = *(const float4*)(src + i + 4);
    bf16x8 o;
    o[0] = f2bf(a.x); o[1] = f2bf(a.y); o[2] = f2bf(a.z); o[3] = f2bf(a.w);
    o[4] = f2bf(b.x); o[5] = f2bf(b.y); o[6] = f2bf(b.z); o[7] = f2bf(b.w);
    *reinterpret_cast<bf16x8*>(dst + i) = o;
  }
}

// ---------------- unified GEMM: C = A[M,K] @ B[N,K]^T (+bias, epilogue) ----------------
// BK=64, double-buffered global_load_lds staging, counted vmcnt, XOR-swizzled LDS.
// EPI 0: proj permuted bf16 store; EPI 1: proj + V-transpose; EPI 2: f32 out store.
template<int BM, int BN, int EPI>
__global__ __launch_bounds__(256, 2) void gemm_bt(const bf16* __restrict__ A,
                                                  const bf16* __restrict__ Bm,
                                                  const float* __restrict__ bias,
                                                  void* __restrict__ OutP,
                                                  int K, int ntn, float scale) {
  constexpr int LA = BM / 32, LB = BN / 32, NL = LA + LB;
  constexpr int ABYTES = BM * 128, BBYTES = BN * 128, HALF = ABYTES + BBYTES;
  constexpr int WM = BM / 2, WN = BN / 2, MR = WM / 16, NR = WN / 16;
  static_assert(NL == 8 || NL == 6, "vmcnt literal");
  __shared__ __align__(16) char lds[2 * HALF];

  int tid = threadIdx.x;
  int w = tid >> 6, l = tid & 63;
  int l15 = l & 15, lg = l >> 4;
  int wr = w >> 1, wc = w & 1;

  // XCD-chunked swizzle; n-tile cycles fastest (A-panel shared by neighbors)
  int bid = blockIdx.x;
  int q8 = gridDim.x >> 3;
  int wg = (bid & 7) * q8 + (bid >> 3);
  int mt = wg / ntn, nt = wg % ntn;
  int m0 = mt * BM, n0 = nt * BN;

  size_t K2 = (size_t)K * 2;
  char* ldsp = (char*)lds;
  const char* Abase = (const char*)A + (size_t)m0 * K2;
  const char* Bbase = (const char*)Bm + (size_t)n0 * K2;

  auto ISSUE = [&](int buf, int kt) {
    const char* As = Abase + (size_t)kt * 128;
    const char* Bs = Bbase + (size_t)kt * 128;
    char* db = ldsp + buf * HALF;
#pragma unroll
    for (int i = 0; i < LA; ++i) {
      int c = tid + i * 256, row = c >> 3;
      __builtin_amdgcn_global_load_lds((glob_cv*)(As + (size_t)row * K2 + 16 * ((c & 7) ^ (row & 7))),
                                       (lds_v*)(db + c * 16), 16, 0, 0);
    }
#pragma unroll
    for (int i = 0; i < LB; ++i) {
      int c = tid + i * 256, row = c >> 3;
      __builtin_amdgcn_global_load_lds((glob_cv*)(Bs + (size_t)row * K2 + 16 * ((c & 7) ^ (row & 7))),
                                       (lds_v*)(db + ABYTES + c * 16), 16, 0, 0);
    }
  };

  f32x4 acc[MR][NR];
#pragma unroll
  for (int mi = 0; mi < MR; ++mi)
#pragma unroll
    for (int ni = 0; ni < NR; ++ni) acc[mi][ni] = f32x4{0.f, 0.f, 0.f, 0.f};

  int NT = K >> 6;
  ISSUE(0, 0);
  for (int kt = 0; kt < NT; ++kt) {
    int cur = kt & 1;
    if (kt + 1 < NT) {
      ISSUE(cur ^ 1, kt + 1);
      if constexpr (NL == 8) asm volatile("s_waitcnt vmcnt(8)" ::: "memory");
      else asm volatile("s_waitcnt vmcnt(6)" ::: "memory");
    } else {
      asm volatile("s_waitcnt vmcnt(0)" ::: "memory");
    }
    __builtin_amdgcn_s_barrier();
    __builtin_amdgcn_sched_barrier(0);

    const char* bufc = ldsp + cur * HALF;
#pragma unroll
    for (int kb2 = 0; kb2 < 2; ++kb2) {
      int swz = 16 * ((kb2 * 4 + lg) ^ (l15 & 7));
      bf16x8 af[MR], bfr[NR];
#pragma unroll
      for (int mi = 0; mi < MR; ++mi)
        af[mi] = *(const bf16x8*)(bufc + (wr * WM + mi * 16 + l15) * 128 + swz);
#pragma unroll
      for (int ni = 0; ni < NR; ++ni)
        bfr[ni] = *(const bf16x8*)(bufc + ABYTES + (wc * WN + ni * 16 + l15) * 128 + swz);
#pragma unroll
      for (int mi = 0; mi < MR; ++mi)
#pragma unroll
        for (int ni = 0; ni < NR; ++ni)
          acc[mi][ni] = __builtin_amdgcn_mfma_f32_16x16x32_bf16(af[mi], bfr[ni], acc[mi][ni], 0, 0, 0);
    }
    __builtin_amdgcn_sched_barrier(0);
    __builtin_amdgcn_s_barrier();
  }

  // ---- epilogue ----
#pragma unroll
  for (int ni = 0; ni < NR; ++ni) {
    int col = n0 + wc * WN + ni * 16 + l15;
    float bv = bias[col];
#pragma unroll
    for (int mi = 0; mi < MR; ++mi) {
#pragma unroll
      for (int r = 0; r < 4; ++r) {
        float v = acc[mi][ni][r] + bv;
        int row = m0 + wr * WM + mi * 16 + lg * 4 + r;
        if (EPI == 2) {
          ((float*)OutP)[(size_t)row * 256 + col] = v;
        } else {
          int b = row >> 11, s = row & 2047;
          int h = s >> 8;
          int sp = ((s & 255) << 3) | (col >> 8);
          int d = col & 255;
          size_t off = (EPI == 1)
              ? (((size_t)(b * 8 + h) * D_HEAD) + d) * S_LEN + sp    // [B*H, D, S']
              : (((size_t)(b * 8 + h) * S_LEN) + sp) * D_HEAD + d;   // [B*H, S', D]
          ((bf16*)OutP)[off] = __float2bfloat16(v * scale);
        }
      }
    }
  }
}

// ---------------- flash attention (unchanged from R6) ----------------
__global__ __launch_bounds__(256, 2) void attn_kernel(const bf16* __restrict__ Qp,
                                                      const bf16* __restrict__ Kp,
                                                      const bf16* __restrict__ Vt,
                                                      bf16* __restrict__ AL) {
  __shared__ __align__(16) bf16 KVs[2 * 16384];    // 64 KB
  __shared__ __align__(16) bf16 Ps[4][16 * 40];    // per-wave P tile, 5 KB

  int tid = threadIdx.x;
  int w = tid >> 6, l = tid & 63;
  int l15 = l & 15, lg = l >> 4;
  int l31 = l & 31, hl = l >> 5;

  int bid = blockIdx.x;
  int xcd = bid & 7, j = bid >> 3;
  int bh = xcd + 8 * (j >> 5);
  int qt = j & 31;

  const bf16* Qb = Qp + (size_t)bh * S_LEN * D_HEAD;
  const bf16* Kb = Kp + (size_t)bh * S_LEN * D_HEAD;
  const bf16* Vb = Vt + (size_t)bh * (size_t)D_HEAD * S_LEN;

  int q0 = qt * 64 + w * 16;

  bf16x8 qf[8];
#pragma unroll
  for (int kb = 0; kb < 8; ++kb)
    qf[kb] = *(const bf16x8*)(Qb + (size_t)(q0 + l15) * D_HEAD + kb * 32 + lg * 8);

  f32x4 acc[16];
#pragma unroll
  for (int n = 0; n < 16; ++n) acc[n] = f32x4{0.f, 0.f, 0.f, 0.f};
  f32x4 acc_l = f32x4{0.f, 0.f, 0.f, 0.f};
  float m_r[4] = {-__builtin_inff(), -__builtin_inff(), -__builtin_inff(), -__builtin_inff()};

  bf16x8 ones;
#pragma unroll
  for (int i = 0; i < 8; ++i) ones[i] = (short)0x3F80;

  const float THR = 4.0f;

  const char* pK = (const char*)Kb + (size_t)l31 * 512 + (size_t)(w * 256 + hl * 16);
  const char* pV = (const char*)Vb + (size_t)l * 4096 + (size_t)((w - 2) * 32);
  int dK = w * 8192 + l * 16;
  int dV = 16384 + (w - 2) * 8192 + l * 16;
  char* ldsBase = (char*)&KVs[0];

  auto ISSUE = [&](int buf) {
    char* bb = ldsBase + buf * 32768;
    if (w < 2) {
#pragma unroll
      for (int i = 0; i < 8; ++i)
        __builtin_amdgcn_global_load_lds((glob_cv*)(pK + i * 32),
                                         (lds_v*)(bb + dK + i * 1024), 16, 0, 0);
      pK += 32 * 512;
    } else {
#pragma unroll
      for (int i = 0; i < 8; ++i)
        __builtin_amdgcn_global_load_lds((glob_cv*)(pV + (i & 3) * 262144 + (i >> 2) * 16),
                                         (lds_v*)(bb + dV + i * 1024), 16, 0, 0);
      pV += 64;
    }
  };

  int krd = lg * 256 + l15 * 8;
  int vrd = 8192 + lg * 2048 + l15 * 8;
  int prd = l15 * 40 + lg * 8;

  ISSUE(0);

  for (int kt = 0; kt < 64; ++kt) {
    int cur = kt & 1;
    if (kt < 63) {
      ISSUE(cur ^ 1);
      asm volatile("s_waitcnt vmcnt(8)" ::: "memory");
    } else {
      asm volatile("s_waitcnt vmcnt(0)" ::: "memory");
    }
    __builtin_amdgcn_s_barrier();
    __builtin_amdgcn_sched_barrier(0);

    const bf16* bufp = &KVs[cur * 16384];

    f32x4 sc0 = f32x4{0.f, 0.f, 0.f, 0.f}, sc1 = f32x4{0.f, 0.f, 0.f, 0.f};
    __builtin_amdgcn_s_setprio(1);
#pragma unroll
    for (int kb = 0; kb < 8; ++kb) {
      bf16x8 kf0 = *(const bf16x8*)(bufp + krd + kb * 1024);
      bf16x8 kf1 = *(const bf16x8*)(bufp + krd + kb * 1024 + 128);
      sc0 = __builtin_amdgcn_mfma_f32_16x16x32_bf16(qf[kb], kf0, sc0, 0, 0, 0);
      sc1 = __builtin_amdgcn_mfma_f32_16x16x32_bf16(qf[kb], kf1, sc1, 0, 0, 0);
    }
    __builtin_amdgcn_s_setprio(0);

    float pm[4];
#pragma unroll
    for (int r = 0; r < 4; ++r) {
      float v = fmaxf(sc0[r], sc1[r]);
      v = fmaxf(v, __shfl_xor(v, 1));
      v = fmaxf(v, __shfl_xor(v, 2));
      v = fmaxf(v, __shfl_xor(v, 4));
      v = fmaxf(v, __shfl_xor(v, 8));
      pm[r] = v;
    }
    bool need = (pm[0] > m_r[0] + THR) || (pm[1] > m_r[1] + THR) ||
                (pm[2] > m_r[2] + THR) || (pm[3] > m_r[3] + THR);
    if (__ballot(need)) {
#pragma unroll
      for (int r = 0; r < 4; ++r) {
        float mn = fmaxf(m_r[r], pm[r]);
        float esc = __expf(m_r[r] - mn);
        m_r[r] = mn;
#pragma unroll
        for (int n = 0; n < 16; ++n) acc[n][r] *= esc;
        acc_l[r] *= esc;
      }
    }
#pragma unroll
    for (int r = 0; r < 4; ++r) {
      float p0 = __expf(sc0[r] - m_r[r]);
      float p1 = __expf(sc1[r] - m_r[r]);
      int qr = lg * 4 + r;
      Ps[w][qr * 40 + l15] = __float2bfloat16(p0);
      Ps[w][qr * 40 + 16 + l15] = __float2bfloat16(p1);
    }

    bf16x8 pa = *(const bf16x8*)(&Ps[w][prd]);
    __builtin_amdgcn_s_setprio(1);
    acc_l = __builtin_amdgcn_mfma_f32_16x16x32_bf16(pa, ones, acc_l, 0, 0, 0);
#pragma unroll
    for (int n = 0; n < 16; ++n) {
      bf16x8 vbf = *(const bf16x8*)(bufp + vrd + n * 128);
      acc[n] = __builtin_amdgcn_mfma_f32_16x16x32_bf16(pa, vbf, acc[n], 0, 0, 0);
    }
    __builtin_amdgcn_s_setprio(0);

    __builtin_amdgcn_s_barrier();
  }

  int b = bh >> 3, h = bh & 7;
#pragma unroll
  for (int r = 0; r < 4; ++r) {
    float inv = 1.0f / acc_l[r];
    int q = q0 + lg * 4 + r;
    bf16* orow = AL + ((size_t)b * S_LEN + q) * HD + h * D_HEAD;
#pragma unroll
    for (int n = 0; n < 16; ++n)
      orow[n * 16 + l15] = __float2bfloat16(acc[n][r] * inv);
  }
}

extern "C" void kernel_launch(void* const* d_in, const int* in_sizes, int n_in,
                              void* d_out, int out_size, void* d_ws, size_t ws_size,
                              hipStream_t stream) {
  (void)in_sizes; (void)n_in; (void)out_size; (void)ws_size;
  const float* query  = (const float*)d_in[0];
  const float* key    = (const float*)d_in[1];
  const float* values = (const float*)d_in[2];
  const float* Wq = (const float*)d_in[3];
  const float* bq = (const float*)d_in[4];
  const float* Wk = (const float*)d_in[5];
  const float* bk = (const float*)d_in[6];
  const float* Wv = (const float*)d_in[7];
  const float* bv = (const float*)d_in[8];
  const float* Wo = (const float*)d_in[9];
  const float* bo = (const float*)d_in[10];
  float* out = (float*)d_out;

  bf16* ws = (bf16*)d_ws;
  const size_t NP = (size_t)B_SZ * H_N * S_LEN * D_HEAD;  // 16,777,216
  const size_t NW = (size_t)HD * D_HEAD;                  // 524,288
  const size_t NX = (size_t)B_SZ * S_LEN * D_HEAD;        // 2,097,152
  bf16* Qp  = ws;
  bf16* Kp  = Qp + NP;
  bf16* Vtp = Kp + NP;   // V transposed: [B*H, D, S']
  bf16* ALb = Vtp + NP;
  bf16* Wqb = ALb + NP;
  bf16* Wkb = Wqb + NW;
  bf16* Wvb = Wkb + NW;
  bf16* Wob = Wvb + NW;
  // X bf16 copies live in the ALb region (dead until attn writes it)
  bf16* Xqb = ALb;
  bf16* Xkb = ALb + NX;
  bf16* Xvb = ALb + 2 * NX;

  cvt_kernel<<<256, 256, 0, stream>>>(Wq, Wqb, (int)NW);
  cvt_kernel<<<256, 256, 0, stream>>>(Wk, Wkb, (int)NW);
  cvt_kernel<<<256, 256, 0, stream>>>(Wv, Wvb, (int)NW);
  cvt_kernel<<<256, 256, 0, stream>>>(Wo, Wob, (int)NW);
  cvt_kernel<<<1024, 256, 0, stream>>>(query,  Xqb, (int)NX);
  cvt_kernel<<<1024, 256, 0, stream>>>(key,    Xkb, (int)NX);
  cvt_kernel<<<1024, 256, 0, stream>>>(values, Xvb, (int)NX);

  // proj: M=8192 (64 m-tiles), N=2048 (16 n-tiles) -> 1024 blocks
  gemm_bt<128, 128, 0><<<1024, 256, 0, stream>>>(Xqb, Wqb, bq, Qp,  256, 16, 1.0f / 16.0f);
  gemm_bt<128, 128, 0><<<1024, 256, 0, stream>>>(Xkb, Wkb, bk, Kp,  256, 16, 1.0f);
  gemm_bt<128, 128, 1><<<1024, 256, 0, stream>>>(Xvb, Wvb, bv, Vtp, 256, 16, 1.0f);

  attn_kernel<<<1024, 256, 0, stream>>>(Qp, Kp, Vtp, ALb);

  // out: M=8192 (64 m-tiles), N=256 (4 n-tiles of 64) -> 256 blocks
  gemm_bt<128, 64, 2><<<256, 256, 0, stream>>>(ALb, Wob, bo, out, 2048, 4, 1.0f);
}